// Round 5
// baseline (1021.742 us; speedup 1.0000x reference)
//
#include <hip/hip_runtime.h>
#include <hip/hip_bf16.h>

typedef _Float16 f16x8 __attribute__((ext_vector_type(8)));
typedef float f32x4 __attribute__((ext_vector_type(4)));

#define H 128
#define FEAT 7

__device__ __forceinline__ float conv3(float x, float w, float b) {
    x = fmaxf(fmaf(w, x, b), 0.f);
    x = fmaxf(fmaf(w, x, b), 0.f);
    x = fmaxf(fmaf(w, x, b), 0.f);
    return x;
}
__device__ __forceinline__ float sigm(float x) { return 1.f / (1.f + __expf(-x)); }

// Pack fp32 row-major W[k][n] -> f16 MFMA-B-fragment layout: P[((k>>3)*N + n)*8 + (k&7)]
__global__ __launch_bounds__(256) void pack_weights(
    const float* __restrict__ Wr, const float* __restrict__ Wh, const float* __restrict__ Wz,
    _Float16* __restrict__ Pr, _Float16* __restrict__ Ph, _Float16* __restrict__ Pz)
{
    int idx = blockIdx.x * 256 + threadIdx.x;
    if (idx < 384 * 384) {
        int k = idx / 384, n = idx % 384;
        Pr[((size_t)(k >> 3) * 384 + n) * 8 + (k & 7)] = (_Float16)Wr[idx];
    }
    if (idx < 384 * 128) {
        int k = idx / 128, n = idx % 128;
        Ph[((size_t)(k >> 3) * 128 + n) * 8 + (k & 7)] = (_Float16)Wh[idx];
    }
    if (idx < 512 * 512) {
        int k = idx / 512, n = idx % 512;
        Pz[((size_t)(k >> 3) * 512 + n) * 8 + (k & 7)] = (_Float16)Wz[idx];
    }
}

// Leaf embedding: emb9 = conv3(contents9 @ Wu + bu), f16 out. Streaming, VALU-bound.
__global__ __launch_bounds__(256) void emb9_kernel(
    const float* __restrict__ contents,
    const float* __restrict__ Wu, const float* __restrict__ bu,
    const float* __restrict__ convw, const float* __restrict__ convb,
    _Float16* __restrict__ emb)
{
    int idx = blockIdx.x * 256 + threadIdx.x;
    int row = idx >> 7, h = idx & 127;
    const float* c = contents + (size_t)row * FEAT;
    float acc = bu[h];
#pragma unroll
    for (int k = 0; k < FEAT; k++) acc = fmaf(c[k], Wu[k * H + h], acc);
    emb[idx] = (_Float16)conv3(acc, convw[0], convb[0]);
}

// Fused level kernel. ROWS = RT*16 rows per 256-thread block.
// LDS: s_hhu[ROWS][392] + 16-row pool (x pass buffer, later hH buffer).
template<int RT>
__global__ __launch_bounds__(256, 4) void level_kernel(
    const float* __restrict__ contents,     // pre-offset, (n,7)
    const int* __restrict__ children,       // pre-offset, (n,2)
    const _Float16* __restrict__ embPrev,
    _Float16* __restrict__ embOut,
    float* __restrict__ finalOut,           // non-null only at level 0
    const float* __restrict__ Wu, const float* __restrict__ bu,
    const _Float16* __restrict__ Pr, const float* __restrict__ br,
    const _Float16* __restrict__ Ph, const float* __restrict__ bh,
    const _Float16* __restrict__ Pz, const float* __restrict__ bz,
    const float* __restrict__ convw, const float* __restrict__ convb)
{
    constexpr int ROWS = RT * 16;
    __shared__ __align__(16) _Float16 s_hhu[ROWS][392];      // [h_L | h_R | u]
    __shared__ __align__(16) _Float16 s_pool[16 * 392];      // 12544 B
    _Float16 (* const s_x)[392]  = (_Float16 (*)[392])s_pool;  // 16-row x pass buffer
    _Float16 (* const s_hH)[136] = (_Float16 (*)[136])s_pool;  // ROWS-row hH after passes

    const int t = threadIdx.x;
    const int row0 = blockIdx.x * ROWS;
    const int col0 = t & 127;
    const int thalf = t >> 7;
    const float cw = convw[0], cb = convb[0];

    // ---- Stage A: u = conv3(c @ Wu + bu) -> s_hhu[:, 256:384]
    {
        float wcol[FEAT];
#pragma unroll
        for (int k = 0; k < FEAT; k++) wcol[k] = Wu[k * H + col0];
        const float bucol = bu[col0];
#pragma unroll
        for (int i = 0; i < ROWS / 2; i++) {
            int r = 2 * i + thalf;
            const float* c = contents + (size_t)(row0 + r) * FEAT;
            float acc = bucol;
#pragma unroll
            for (int k = 0; k < FEAT; k++) acc = fmaf(c[k], wcol[k], acc);
            s_hhu[r][256 + col0] = (_Float16)conv3(acc, cw, cb);
        }
    }

    // ---- Stage B: gather children embeddings (16B vector loads)
    {
        int rp = t >> 4, chunk = t & 15;
#pragma unroll
        for (int p = 0; p < 2 * RT; p++) {
            int cr = p * 16 + rp;       // child slot 0..2*ROWS-1
            int r = cr >> 1, s = cr & 1;
            int child = children[row0 * 2 + cr];
            uint4 v = *(const uint4*)(embPrev + (size_t)child * H + chunk * 8);
            *(uint4*)&s_hhu[r][s * 128 + chunk * 8] = v;
        }
    }
    __syncthreads();

    const int lane = t & 63;
    const int w = t >> 6;      // wave 0..3
    const int q = lane >> 4;   // 0..3
    const int ln = lane & 15;

    _Float16 xhold[6][RT > 1 ? RT - 1 : 1][4];   // x rows 16.., held across stage-D passes

    // ---- Stage C: r = sigmoid(hhu @ Wr + br); x = r*hhu  (N=384, K=384)
    {
        const f16x8* PB = (const f16x8*)Pr + (w * 96 + ln);
        f32x4 acc[6][RT];
#pragma unroll
        for (int c = 0; c < 6; c++)
#pragma unroll
            for (int rt = 0; rt < RT; rt++) acc[c][rt] = (f32x4){0, 0, 0, 0};
        f16x8 a[RT], b[6];
#pragma unroll
        for (int rt = 0; rt < RT; rt++) a[rt] = *(const f16x8*)&s_hhu[rt * 16 + ln][q * 8];
#pragma unroll
        for (int c = 0; c < 6; c++) b[c] = PB[(size_t)q * 384 + c * 16];
#pragma unroll
        for (int kk = 0; kk < 12; kk++) {
            f16x8 ca[RT], cb6[6];
#pragma unroll
            for (int rt = 0; rt < RT; rt++) ca[rt] = a[rt];
#pragma unroll
            for (int c = 0; c < 6; c++) cb6[c] = b[c];
            if (kk < 11) {
                int kb = (kk + 1) * 4 + q;
#pragma unroll
                for (int c = 0; c < 6; c++) b[c] = PB[(size_t)kb * 384 + c * 16];
#pragma unroll
                for (int rt = 0; rt < RT; rt++)
                    a[rt] = *(const f16x8*)&s_hhu[rt * 16 + ln][(kk + 1) * 32 + q * 8];
            }
#pragma unroll
            for (int c = 0; c < 6; c++)
#pragma unroll
                for (int rt = 0; rt < RT; rt++)
                    acc[c][rt] = __builtin_amdgcn_mfma_f32_16x16x32_f16(ca[rt], cb6[c], acc[c][rt], 0, 0, 0);
        }
#pragma unroll
        for (int c = 0; c < 6; c++) {
            int colg = w * 96 + c * 16 + ln;
            float bb = br[colg];
#pragma unroll
            for (int rt = 0; rt < RT; rt++)
#pragma unroll
                for (int reg = 0; reg < 4; reg++) {
                    int row = rt * 16 + q * 4 + reg;
                    float rv = sigm(acc[c][rt][reg] + bb);
                    _Float16 xv = (_Float16)(rv * (float)s_hhu[row][colg]);
                    if (rt == 0) s_x[q * 4 + reg][colg] = xv;
                    else xhold[c][rt - 1][reg] = xv;
                }
        }
    }
    __syncthreads();

    // ---- Stage D: h_H = conv3(x @ Wh + bh), RT 16-row passes; hH held in regs
    float hhold[RT][2][4];
    {
        const f16x8* PBh = (const f16x8*)Ph + (w * 32 + ln);
#pragma unroll
        for (int pass = 0; pass < RT; pass++) {
            f32x4 acc2[2];
            acc2[0] = (f32x4){0, 0, 0, 0}; acc2[1] = (f32x4){0, 0, 0, 0};
            f16x8 a1 = *(const f16x8*)&s_x[ln][q * 8];
            f16x8 b2[2];
            b2[0] = PBh[(size_t)q * 128];
            b2[1] = PBh[(size_t)q * 128 + 16];
#pragma unroll
            for (int kk = 0; kk < 12; kk++) {
                f16x8 ca = a1, cb0 = b2[0], cb1 = b2[1];
                if (kk < 11) {
                    int kb = (kk + 1) * 4 + q;
                    b2[0] = PBh[(size_t)kb * 128];
                    b2[1] = PBh[(size_t)kb * 128 + 16];
                    a1 = *(const f16x8*)&s_x[ln][(kk + 1) * 32 + q * 8];
                }
                acc2[0] = __builtin_amdgcn_mfma_f32_16x16x32_f16(ca, cb0, acc2[0], 0, 0, 0);
                acc2[1] = __builtin_amdgcn_mfma_f32_16x16x32_f16(ca, cb1, acc2[1], 0, 0, 0);
            }
#pragma unroll
            for (int cc = 0; cc < 2; cc++) {
                float bb = bh[w * 32 + cc * 16 + ln];
#pragma unroll
                for (int reg = 0; reg < 4; reg++)
                    hhold[pass][cc][reg] = conv3(acc2[cc][reg] + bb, cw, cb);
            }
            __syncthreads();   // this pass's x reads complete
            if (pass < RT - 1) {
                // refill pass buffer with x rows (pass+1)*16 ..
#pragma unroll
                for (int c = 0; c < 6; c++) {
                    int colg = w * 96 + c * 16 + ln;
#pragma unroll
                    for (int reg = 0; reg < 4; reg++)
                        s_x[q * 4 + reg][colg] = xhold[c][pass][reg];
                }
                __syncthreads();
            }
        }
    }
    // pool is free: dump hH registers -> s_hH (ROWS rows)
#pragma unroll
    for (int pass = 0; pass < RT; pass++)
#pragma unroll
        for (int cc = 0; cc < 2; cc++) {
            int colg = w * 32 + cc * 16 + ln;
#pragma unroll
            for (int reg = 0; reg < 4; reg++)
                s_hH[pass * 16 + q * 4 + reg][colg] = (_Float16)hhold[pass][cc][reg];
        }
    __syncthreads();

    // ---- Stage E: z = [h_H | hhu] @ Wz + bz; softmax gate; store (N=512, K=512)
    {
        const f16x8* PBz = (const f16x8*)Pz + ln;
#pragma unroll
        for (int sub = 0; sub < 2; sub++) {
            int nc = w * 32 + sub * 16;
            const f16x8* PL = PBz + nc;
            f32x4 acc[4][RT];
#pragma unroll
            for (int q4 = 0; q4 < 4; q4++)
#pragma unroll
                for (int rt = 0; rt < RT; rt++) acc[q4][rt] = (f32x4){0, 0, 0, 0};
            f16x8 a[RT], b0[4], b1[4];
#pragma unroll
            for (int rt = 0; rt < RT; rt++) a[rt] = *(const f16x8*)&s_hH[rt * 16 + ln][q * 8];
#pragma unroll
            for (int q4 = 0; q4 < 4; q4++) b0[q4] = PL[(size_t)q * 512 + q4 * 128];
#pragma unroll
            for (int q4 = 0; q4 < 4; q4++) b1[q4] = PL[(size_t)(4 + q) * 512 + q4 * 128];
#pragma unroll
            for (int kk = 0; kk < 16; kk++) {
                f16x8 ca[RT], cb4[4];
#pragma unroll
                for (int rt = 0; rt < RT; rt++) ca[rt] = a[rt];
#pragma unroll
                for (int q4 = 0; q4 < 4; q4++) { cb4[q4] = b0[q4]; b0[q4] = b1[q4]; }
                if (kk < 14) {
                    int kb = (kk + 2) * 4 + q;
#pragma unroll
                    for (int q4 = 0; q4 < 4; q4++) b1[q4] = PL[(size_t)kb * 512 + q4 * 128];
                }
                if (kk < 15) {
                    if (kk + 1 < 4) {
#pragma unroll
                        for (int rt = 0; rt < RT; rt++)
                            a[rt] = *(const f16x8*)&s_hH[rt * 16 + ln][(kk + 1) * 32 + q * 8];
                    } else {
                        int k0 = (kk + 1) * 32 - 128;
#pragma unroll
                        for (int rt = 0; rt < RT; rt++)
                            a[rt] = *(const f16x8*)&s_hhu[rt * 16 + ln][k0 + q * 8];
                    }
                }
#pragma unroll
                for (int q4 = 0; q4 < 4; q4++)
#pragma unroll
                    for (int rt = 0; rt < RT; rt++)
                        acc[q4][rt] = __builtin_amdgcn_mfma_f32_16x16x32_f16(ca[rt], cb4[q4], acc[q4][rt], 0, 0, 0);
            }
            int colg = nc + ln;
            float bz0 = bz[colg], bz1 = bz[128 + colg], bz2 = bz[256 + colg], bz3 = bz[384 + colg];
#pragma unroll
            for (int rt = 0; rt < RT; rt++)
#pragma unroll
                for (int reg = 0; reg < 4; reg++) {
                    int row = rt * 16 + q * 4 + reg;
                    float z0 = acc[0][rt][reg] + bz0;
                    float z1 = acc[1][rt][reg] + bz1;
                    float z2 = acc[2][rt][reg] + bz2;
                    float z3 = acc[3][rt][reg] + bz3;
                    float m = fmaxf(fmaxf(z0, z1), fmaxf(z2, z3));
                    float e0 = __expf(z0 - m), e1 = __expf(z1 - m), e2 = __expf(z2 - m), e3 = __expf(z3 - m);
                    float inv = 1.f / (e0 + e1 + e2 + e3);
                    float hH = (float)s_hH[row][colg];
                    float hL = (float)s_hhu[row][colg];
                    float hR = (float)s_hhu[row][128 + colg];
                    float uu = (float)s_hhu[row][256 + colg];
                    float e = (e0 * hH + e1 * hL + e2 * hR + e3 * uu) * inv;
                    size_t gidx = (size_t)(row0 + row) * H + colg;
                    if (finalOut) finalOut[gidx] = e;
                    else embOut[gidx] = (_Float16)e;
                }
        }
    }
}

extern "C" void kernel_launch(void* const* d_in, const int* in_sizes, int n_in,
                              void* d_out, int out_size, void* d_ws, size_t ws_size,
                              hipStream_t stream) {
    const float* contents = (const float*)d_in[0];
    const int*   children = (const int*)d_in[1];
    const float* Wu = (const float*)d_in[2];
    const float* bu = (const float*)d_in[3];
    const float* Wh = (const float*)d_in[4];
    const float* bh = (const float*)d_in[5];
    const float* Wz = (const float*)d_in[6];
    const float* bz = (const float*)d_in[7];
    const float* Wr = (const float*)d_in[8];
    const float* br = (const float*)d_in[9];
    const float* convw = (const float*)d_in[10];
    const float* convb = (const float*)d_in[11];
    float* out = (float*)d_out;

    // Workspace: [packed weights 1MB][region X 128MB][region Y 64MB]
    // emb ping-pong: emb9 -> X, L8 -> Y, L7 -> X, L6 -> Y, ... (old data always dead)
    _Float16* Pr = (_Float16*)d_ws;
    _Float16* Ph = Pr + 384 * 384;
    _Float16* Pz = Ph + 384 * 128;
    _Float16* regX = (_Float16*)((char*)d_ws + (1 << 20));
    _Float16* regY = regX + (size_t)524288 * H;

    auto OFFS = [](int j) -> long long { return 1024LL * ((1LL << j) - 1); };

    pack_weights<<<(512 * 512 + 255) / 256, 256, 0, stream>>>(Wr, Wh, Wz, Pr, Ph, Pz);

    // Leaf: emb9 = conv3(contents9 @ Wu + bu)
    emb9_kernel<<<(524288 * H) / 256, 256, 0, stream>>>(
        contents + OFFS(9) * FEAT, Wu, bu, convw, convb, regX);

    _Float16* prev = regX;
    _Float16* cur  = regY;
    for (int j = 8; j >= 0; j--) {
        int n = 1024 << j;
        float* fo = (j == 0 ? out : nullptr);
        if (j >= 4) {
            level_kernel<2><<<n / 32, 256, 0, stream>>>(
                contents + OFFS(j) * FEAT, children + OFFS(j) * 2,
                prev, cur, fo, Wu, bu, Pr, br, Ph, bh, Pz, bz, convw, convb);
        } else {
            level_kernel<1><<<n / 16, 256, 0, stream>>>(
                contents + OFFS(j) * FEAT, children + OFFS(j) * 2,
                prev, cur, fo, Wu, bu, Pr, br, Ph, bh, Pz, bz, convw, convb);
        }
        _Float16* tmp = prev; prev = cur; cur = tmp;
    }
}

// Round 6
// 969.634 us; speedup vs baseline: 1.0537x; 1.0537x over previous
//
#include <hip/hip_runtime.h>
#include <hip/hip_bf16.h>

typedef _Float16 f16x8 __attribute__((ext_vector_type(8)));
typedef _Float16 f16x4 __attribute__((ext_vector_type(4)));
typedef float f32x4 __attribute__((ext_vector_type(4)));

#define H 128
#define FEAT 7

__device__ __forceinline__ float conv3(float x, float w, float b) {
    x = fmaxf(fmaf(w, x, b), 0.f);
    x = fmaxf(fmaf(w, x, b), 0.f);
    x = fmaxf(fmaf(w, x, b), 0.f);
    return x;
}
__device__ __forceinline__ float sigm(float x) { return 1.f / (1.f + __expf(-x)); }

// Pack fp32 row-major W[k][n] -> f16 MFMA fragment layout: P[((k>>3)*N + n)*8 + (k&7)]
// (works as A-operand with m=n-index: lane ln holds channel tile+ln, k=q*8+j)
__global__ __launch_bounds__(256) void pack_weights(
    const float* __restrict__ Wr, const float* __restrict__ Wh, const float* __restrict__ Wz,
    _Float16* __restrict__ Pr, _Float16* __restrict__ Ph, _Float16* __restrict__ Pz)
{
    int idx = blockIdx.x * 256 + threadIdx.x;
    if (idx < 384 * 384) {
        int k = idx / 384, n = idx % 384;
        Pr[((size_t)(k >> 3) * 384 + n) * 8 + (k & 7)] = (_Float16)Wr[idx];
    }
    if (idx < 384 * 128) {
        int k = idx / 128, n = idx % 128;
        Ph[((size_t)(k >> 3) * 128 + n) * 8 + (k & 7)] = (_Float16)Wh[idx];
    }
    if (idx < 512 * 512) {
        int k = idx / 512, n = idx % 512;
        Pz[((size_t)(k >> 3) * 512 + n) * 8 + (k & 7)] = (_Float16)Wz[idx];
    }
}

// Leaf embedding: emb9 = conv3(contents9 @ Wu + bu). 8 outputs/thread, 16B stores.
__global__ __launch_bounds__(256) void emb9_kernel(
    const float* __restrict__ contents,
    const float* __restrict__ Wu, const float* __restrict__ bu,
    const float* __restrict__ convw, const float* __restrict__ convb,
    _Float16* __restrict__ emb)
{
    int idx = blockIdx.x * 256 + threadIdx.x;   // one thread per 8 outputs
    int row = idx >> 4, h8 = (idx & 15) * 8;
    const float* c = contents + (size_t)row * FEAT;
    float cv[FEAT];
#pragma unroll
    for (int k = 0; k < FEAT; k++) cv[k] = c[k];
    f32x4 acc0 = *(const f32x4*)&bu[h8];
    f32x4 acc1 = *(const f32x4*)&bu[h8 + 4];
#pragma unroll
    for (int k = 0; k < FEAT; k++) {
        f32x4 w0 = *(const f32x4*)&Wu[k * H + h8];
        f32x4 w1 = *(const f32x4*)&Wu[k * H + h8 + 4];
#pragma unroll
        for (int j = 0; j < 4; j++) {
            acc0[j] = fmaf(cv[k], w0[j], acc0[j]);
            acc1[j] = fmaf(cv[k], w1[j], acc1[j]);
        }
    }
    float cw = convw[0], cb = convb[0];
    f16x8 o;
#pragma unroll
    for (int j = 0; j < 4; j++) o[j] = (_Float16)conv3(acc0[j], cw, cb);
#pragma unroll
    for (int j = 0; j < 4; j++) o[4 + j] = (_Float16)conv3(acc1[j], cw, cb);
    *(f16x8*)&emb[(size_t)idx * 8] = o;
}

// Fused level kernel, weights-as-A / activations-as-B MFMA.
// ROWS = RT*16 rows per 256-thread block. Output D[channel][row]: lane holds
// 4 contiguous channels (q*4+reg) of one row (ln) -> vectorized epilogues.
template<int RT>
__global__ __launch_bounds__(256, 4) void level_kernel(
    const float* __restrict__ contents,     // pre-offset, (n,7)
    const int* __restrict__ children,       // pre-offset, (n,2)
    const _Float16* __restrict__ embPrev,
    _Float16* __restrict__ embOut,
    float* __restrict__ finalOut,           // non-null only at level 0
    const float* __restrict__ Wu, const float* __restrict__ bu,
    const _Float16* __restrict__ Pr, const float* __restrict__ br,
    const _Float16* __restrict__ Ph, const float* __restrict__ bh,
    const _Float16* __restrict__ Pz, const float* __restrict__ bz,
    const float* __restrict__ convw, const float* __restrict__ convb)
{
    constexpr int ROWS = RT * 16;
    __shared__ __align__(16) _Float16 s_hhu[ROWS][392];      // [h_L | h_R | u]
    __shared__ __align__(16) _Float16 s_pool[16 * 392];      // 12544 B
    _Float16 (* const s_x)[392]  = (_Float16 (*)[392])s_pool;  // 16-row x pass buffer
    _Float16 (* const s_hH)[136] = (_Float16 (*)[136])s_pool;  // ROWS-row hH after passes

    const int t = threadIdx.x;
    const int row0 = blockIdx.x * ROWS;
    const int col0 = t & 127;
    const int thalf = t >> 7;
    const float cw = convw[0], cb = convb[0];

    // ---- Stage A: u = conv3(c @ Wu + bu) -> s_hhu[:, 256:384]
    {
        float wcol[FEAT];
#pragma unroll
        for (int k = 0; k < FEAT; k++) wcol[k] = Wu[k * H + col0];
        const float bucol = bu[col0];
#pragma unroll
        for (int i = 0; i < ROWS / 2; i++) {
            int r = 2 * i + thalf;
            const float* c = contents + (size_t)(row0 + r) * FEAT;
            float acc = bucol;
#pragma unroll
            for (int k = 0; k < FEAT; k++) acc = fmaf(c[k], wcol[k], acc);
            s_hhu[r][256 + col0] = (_Float16)conv3(acc, cw, cb);
        }
    }

    // ---- Stage B: gather children embeddings (16B vector loads)
    {
        int rp = t >> 4, chunk = t & 15;
#pragma unroll
        for (int p = 0; p < 2 * RT; p++) {
            int cr = p * 16 + rp;       // child slot
            int r = cr >> 1, s = cr & 1;
            int child = children[row0 * 2 + cr];
            uint4 v = *(const uint4*)(embPrev + (size_t)child * H + chunk * 8);
            *(uint4*)&s_hhu[r][s * 128 + chunk * 8] = v;
        }
    }
    __syncthreads();

    const int lane = t & 63;
    const int w = t >> 6;      // wave 0..3
    const int q = lane >> 4;   // 0..3
    const int ln = lane & 15;

    f16x4 xhold[6][RT > 1 ? RT - 1 : 1];   // x rows 16.., held across stage-D passes

    // ---- Stage C: r = sigmoid(hhu @ Wr + br); x = r*hhu  (384 ch, K=384)
    {
        const f16x8* PA = (const f16x8*)Pr + (w * 96 + ln);   // weight A-frags
        f32x4 acc[6][RT];
#pragma unroll
        for (int c = 0; c < 6; c++)
#pragma unroll
            for (int rt = 0; rt < RT; rt++) acc[c][rt] = (f32x4){0, 0, 0, 0};
        f16x8 a[RT], wf[6];
#pragma unroll
        for (int rt = 0; rt < RT; rt++) a[rt] = *(const f16x8*)&s_hhu[rt * 16 + ln][q * 8];
#pragma unroll
        for (int c = 0; c < 6; c++) wf[c] = PA[(size_t)q * 384 + c * 16];
#pragma unroll
        for (int kk = 0; kk < 12; kk++) {
            f16x8 ca[RT], cw6[6];
#pragma unroll
            for (int rt = 0; rt < RT; rt++) ca[rt] = a[rt];
#pragma unroll
            for (int c = 0; c < 6; c++) cw6[c] = wf[c];
            if (kk < 11) {
                int kb = (kk + 1) * 4 + q;
#pragma unroll
                for (int c = 0; c < 6; c++) wf[c] = PA[(size_t)kb * 384 + c * 16];
#pragma unroll
                for (int rt = 0; rt < RT; rt++)
                    a[rt] = *(const f16x8*)&s_hhu[rt * 16 + ln][(kk + 1) * 32 + q * 8];
            }
#pragma unroll
            for (int c = 0; c < 6; c++)
#pragma unroll
                for (int rt = 0; rt < RT; rt++)
                    acc[c][rt] = __builtin_amdgcn_mfma_f32_16x16x32_f16(cw6[c], ca[rt], acc[c][rt], 0, 0, 0);
        }
#pragma unroll
        for (int c = 0; c < 6; c++) {
            int chb = w * 96 + c * 16 + q * 4;
            f32x4 bb = *(const f32x4*)&br[chb];
#pragma unroll
            for (int rt = 0; rt < RT; rt++) {
                int row = rt * 16 + ln;
                f16x4 hh = *(const f16x4*)&s_hhu[row][chb];
                f16x4 xv;
#pragma unroll
                for (int reg = 0; reg < 4; reg++) {
                    float rv = sigm(acc[c][rt][reg] + bb[reg]);
                    xv[reg] = (_Float16)(rv * (float)hh[reg]);
                }
                if (rt == 0) *(f16x4*)&s_x[row][chb] = xv;
                else xhold[c][rt - 1] = xv;
            }
        }
    }
    __syncthreads();

    // ---- Stage D: h_H = conv3(x @ Wh + bh), RT 16-row passes; hH held in regs
    f16x4 hhold[RT][2];
    {
        const f16x8* PA = (const f16x8*)Ph + (w * 32 + ln);
#pragma unroll
        for (int pass = 0; pass < RT; pass++) {
            f32x4 acc2[2];
            acc2[0] = (f32x4){0, 0, 0, 0}; acc2[1] = (f32x4){0, 0, 0, 0};
            f16x8 a1 = *(const f16x8*)&s_x[ln][q * 8];
            f16x8 wf2[2];
            wf2[0] = PA[(size_t)q * 128];
            wf2[1] = PA[(size_t)q * 128 + 16];
#pragma unroll
            for (int kk = 0; kk < 12; kk++) {
                f16x8 ca = a1, cw0 = wf2[0], cw1 = wf2[1];
                if (kk < 11) {
                    int kb = (kk + 1) * 4 + q;
                    wf2[0] = PA[(size_t)kb * 128];
                    wf2[1] = PA[(size_t)kb * 128 + 16];
                    a1 = *(const f16x8*)&s_x[ln][(kk + 1) * 32 + q * 8];
                }
                acc2[0] = __builtin_amdgcn_mfma_f32_16x16x32_f16(cw0, ca, acc2[0], 0, 0, 0);
                acc2[1] = __builtin_amdgcn_mfma_f32_16x16x32_f16(cw1, ca, acc2[1], 0, 0, 0);
            }
#pragma unroll
            for (int cc = 0; cc < 2; cc++) {
                int chb = w * 32 + cc * 16 + q * 4;
                f32x4 bb = *(const f32x4*)&bh[chb];
                f16x4 hv;
#pragma unroll
                for (int reg = 0; reg < 4; reg++)
                    hv[reg] = (_Float16)conv3(acc2[cc][reg] + bb[reg], cw, cb);
                hhold[pass][cc] = hv;
            }
            __syncthreads();   // this pass's x reads complete
            if (pass < RT - 1) {
#pragma unroll
                for (int c = 0; c < 6; c++)
                    *(f16x4*)&s_x[ln][w * 96 + c * 16 + q * 4] = xhold[c][pass];
                __syncthreads();
            }
        }
    }
    // pool free: dump hH -> s_hH (b64 writes)
#pragma unroll
    for (int pass = 0; pass < RT; pass++)
#pragma unroll
        for (int cc = 0; cc < 2; cc++)
            *(f16x4*)&s_hH[pass * 16 + ln][w * 32 + cc * 16 + q * 4] = hhold[pass][cc];
    __syncthreads();

    // ---- Stage E: z = [h_H | hhu] @ Wz + bz; softmax gate; store (512 ch, K=512)
    {
        const f16x8* PAz = (const f16x8*)Pz + ln;
#pragma unroll
        for (int sub = 0; sub < 2; sub++) {
            int nc = w * 32 + sub * 16;
            const f16x8* PL = PAz + nc;
            f32x4 acc[4][RT];
#pragma unroll
            for (int q4 = 0; q4 < 4; q4++)
#pragma unroll
                for (int rt = 0; rt < RT; rt++) acc[q4][rt] = (f32x4){0, 0, 0, 0};
            f16x8 a[RT], w0[4], w1[4];
#pragma unroll
            for (int rt = 0; rt < RT; rt++) a[rt] = *(const f16x8*)&s_hH[rt * 16 + ln][q * 8];
#pragma unroll
            for (int q4 = 0; q4 < 4; q4++) w0[q4] = PL[(size_t)q * 512 + q4 * 128];
#pragma unroll
            for (int q4 = 0; q4 < 4; q4++) w1[q4] = PL[(size_t)(4 + q) * 512 + q4 * 128];
#pragma unroll
            for (int kk = 0; kk < 16; kk++) {
                f16x8 ca[RT], cw4[4];
#pragma unroll
                for (int rt = 0; rt < RT; rt++) ca[rt] = a[rt];
#pragma unroll
                for (int q4 = 0; q4 < 4; q4++) { cw4[q4] = w0[q4]; w0[q4] = w1[q4]; }
                if (kk < 14) {
                    int kb = (kk + 2) * 4 + q;
#pragma unroll
                    for (int q4 = 0; q4 < 4; q4++) w1[q4] = PL[(size_t)kb * 512 + q4 * 128];
                }
                if (kk < 15) {
                    if (kk + 1 < 4) {
#pragma unroll
                        for (int rt = 0; rt < RT; rt++)
                            a[rt] = *(const f16x8*)&s_hH[rt * 16 + ln][(kk + 1) * 32 + q * 8];
                    } else {
                        int k0 = (kk + 1) * 32 - 128;
#pragma unroll
                        for (int rt = 0; rt < RT; rt++)
                            a[rt] = *(const f16x8*)&s_hhu[rt * 16 + ln][k0 + q * 8];
                    }
                }
#pragma unroll
                for (int q4 = 0; q4 < 4; q4++)
#pragma unroll
                    for (int rt = 0; rt < RT; rt++)
                        acc[q4][rt] = __builtin_amdgcn_mfma_f32_16x16x32_f16(cw4[q4], ca[rt], acc[q4][rt], 0, 0, 0);
            }
            int chb = nc + q * 4;
            f32x4 bb0 = *(const f32x4*)&bz[chb];
            f32x4 bb1 = *(const f32x4*)&bz[128 + chb];
            f32x4 bb2 = *(const f32x4*)&bz[256 + chb];
            f32x4 bb3 = *(const f32x4*)&bz[384 + chb];
#pragma unroll
            for (int rt = 0; rt < RT; rt++) {
                int row = rt * 16 + ln;
                f16x4 hH4 = *(const f16x4*)&s_hH[row][chb];
                f16x4 hL4 = *(const f16x4*)&s_hhu[row][chb];
                f16x4 hR4 = *(const f16x4*)&s_hhu[row][128 + chb];
                f16x4 u4  = *(const f16x4*)&s_hhu[row][256 + chb];
                f32x4 res;
#pragma unroll
                for (int reg = 0; reg < 4; reg++) {
                    float z0 = acc[0][rt][reg] + bb0[reg];
                    float z1 = acc[1][rt][reg] + bb1[reg];
                    float z2 = acc[2][rt][reg] + bb2[reg];
                    float z3 = acc[3][rt][reg] + bb3[reg];
                    float m = fmaxf(fmaxf(z0, z1), fmaxf(z2, z3));
                    float e0 = __expf(z0 - m), e1 = __expf(z1 - m), e2 = __expf(z2 - m), e3 = __expf(z3 - m);
                    float inv = 1.f / (e0 + e1 + e2 + e3);
                    res[reg] = (e0 * (float)hH4[reg] + e1 * (float)hL4[reg] +
                                e2 * (float)hR4[reg] + e3 * (float)u4[reg]) * inv;
                }
                size_t gbase = (size_t)(row0 + row) * H + chb;
                if (finalOut) {
                    *(f32x4*)&finalOut[gbase] = res;      // 16B store
                } else {
                    f16x4 o;
#pragma unroll
                    for (int reg = 0; reg < 4; reg++) o[reg] = (_Float16)res[reg];
                    *(f16x4*)&embOut[gbase] = o;          // 8B store
                }
            }
        }
    }
}

extern "C" void kernel_launch(void* const* d_in, const int* in_sizes, int n_in,
                              void* d_out, int out_size, void* d_ws, size_t ws_size,
                              hipStream_t stream) {
    const float* contents = (const float*)d_in[0];
    const int*   children = (const int*)d_in[1];
    const float* Wu = (const float*)d_in[2];
    const float* bu = (const float*)d_in[3];
    const float* Wh = (const float*)d_in[4];
    const float* bh = (const float*)d_in[5];
    const float* Wz = (const float*)d_in[6];
    const float* bz = (const float*)d_in[7];
    const float* Wr = (const float*)d_in[8];
    const float* br = (const float*)d_in[9];
    const float* convw = (const float*)d_in[10];
    const float* convb = (const float*)d_in[11];
    float* out = (float*)d_out;

    // Workspace: [packed weights 1MB][region X 128MB][region Y 64MB]
    _Float16* Pr = (_Float16*)d_ws;
    _Float16* Ph = Pr + 384 * 384;
    _Float16* Pz = Ph + 384 * 128;
    _Float16* regX = (_Float16*)((char*)d_ws + (1 << 20));
    _Float16* regY = regX + (size_t)524288 * H;

    auto OFFS = [](int j) -> long long { return 1024LL * ((1LL << j) - 1); };

    pack_weights<<<(512 * 512 + 255) / 256, 256, 0, stream>>>(Wr, Wh, Wz, Pr, Ph, Pz);

    // Leaf: emb9 = conv3(contents9 @ Wu + bu), 8 outputs/thread
    emb9_kernel<<<(524288 * H / 8) / 256, 256, 0, stream>>>(
        contents + OFFS(9) * FEAT, Wu, bu, convw, convb, regX);

    _Float16* prev = regX;
    _Float16* cur  = regY;
    for (int j = 8; j >= 0; j--) {
        int n = 1024 << j;
        float* fo = (j == 0 ? out : nullptr);
        if (j >= 4) {
            level_kernel<2><<<n / 32, 256, 0, stream>>>(
                contents + OFFS(j) * FEAT, children + OFFS(j) * 2,
                prev, cur, fo, Wu, bu, Pr, br, Ph, bh, Pz, bz, convw, convb);
        } else {
            level_kernel<1><<<n / 16, 256, 0, stream>>>(
                contents + OFFS(j) * FEAT, children + OFFS(j) * 2,
                prev, cur, fo, Wu, bu, Pr, br, Ph, bh, Pz, bz, convw, convb);
        }
        _Float16* tmp = prev; prev = cur; cur = tmp;
    }
}